// Round 11
// baseline (392.113 us; speedup 1.0000x reference)
//
#include <hip/hip_runtime.h>
#include <cstdint>

#define B_ 512
#define N_ 150
#define NT 640
#define C1f 144.26950408889634f    // log2(e)/eps, eps=0.01
#define LN2f 0.69314718055994531f
#define SIGMAf 1.0e-4f
#define INV_N (1.0f/150.0f)

// raw hardware transcendentals (1-ULP v_exp_f32 / v_log_f32)
#define EXP2R(x) __builtin_amdgcn_exp2f(x)
#define LOG2R(x) __builtin_amdgcn_logf(x)

// DPP quad-perm reduces (VALU pipe): xor1 = 0xB1, xor2 = 0x4E
#define DPPF(v, c) __int_as_float(__builtin_amdgcn_update_dpp( \
    __float_as_int(v), __float_as_int(v), (c), 0xF, 0xF, false))
#define RED4_ADD(v)  { v = v + DPPF(v, 0xB1); v = v + DPPF(v, 0x4E); }

#define REP10(X) X(0) X(1) X(2) X(3) X(4) X(5) X(6) X(7) X(8) X(9)

// Threefry-2x32, 20 rounds, exactly as JAX's threefry2x32 lowering.
__host__ __device__ __forceinline__ void tf2x32(uint32_t k0, uint32_t k1,
                                                uint32_t x0, uint32_t x1,
                                                uint32_t& o0, uint32_t& o1) {
  uint32_t ks2 = k0 ^ k1 ^ 0x1BD11BDAu;
  x0 += k0; x1 += k1;
#define TFR(r) { x0 += x1; x1 = (x1 << r) | (x1 >> (32 - r)); x1 ^= x0; }
  TFR(13) TFR(15) TFR(26) TFR(6)
  x0 += k1;  x1 += ks2 + 1u;
  TFR(17) TFR(29) TFR(16) TFR(24)
  x0 += ks2; x1 += k0 + 2u;
  TFR(13) TFR(15) TFR(26) TFR(6)
  x0 += k0;  x1 += k1 + 3u;
  TFR(17) TFR(29) TFR(16) TFR(24)
  x0 += k1;  x1 += ks2 + 4u;
  TFR(13) TFR(15) TFR(26) TFR(6)
  x0 += ks2; x1 += k0 + 5u;
#undef TFR
  o0 = x0; o1 = x1;
}

__device__ __forceinline__ uint32_t jax_bits(uint32_t k0, uint32_t k1, uint32_t p) {
  uint32_t a, b; tf2x32(k0, k1, 0u, p, a, b);   // partitionable: counter (0, p)
  return a ^ b;
}

// ==== Fused kernel: Sinkhorn (static K, dual tile, 2 barriers) + sampling ===
// thread (jA = tid>>2, qA = tid&3):
//   ca tile: column jA, rows 40qA..+39   (phase A: colsum of K^T u)
//   rb tile: row    jA, cols 40qA..+39   (phase B: rowsum of K v)
// u/v consumed as aligned b128 multicast reads; single RED4 per phase.
__global__ __launch_bounds__(NT, 5) void cfm_ot_kernel(
    const float* __restrict__ x1g, const float* __restrict__ maskg,
    const float* __restrict__ tg, const float* __restrict__ x0g,
    const float* __restrict__ epsg,
    const float* __restrict__ W1, const float* __restrict__ b1,
    const float* __restrict__ W2, const float* __restrict__ b2,
    float* __restrict__ partials,
    uint32_t kj0, uint32_t kj1, uint32_t k1r0, uint32_t k1r1,
    uint32_t k2r0, uint32_t k2r1)
{
  __shared__ float x1L[480], x0L[480];
  __shared__ __align__(16) float vhat[160];
  __shared__ __align__(16) float uhat[160];
  __shared__ float red[16];
  __shared__ float psiS[152], mskS[152];
  __shared__ float yu[150 * 9];
  __shared__ int   iselS[152];
  float4* vhat4 = (float4*)vhat;
  float4* uhat4 = (float4*)uhat;

  const int b    = blockIdx.x;
  const int tid  = threadIdx.x;
  const int lane = tid & 63;
  const int wid  = tid >> 6;
  const int jA   = tid >> 2;      // 0..159: column (A) / row (B)
  const int qA   = tid & 3;       // 40-element chunk
  const int rcb  = 40 * qA;
  const bool act = (jA < N_);

  if (tid < 480) {
    x1L[tid] = (tid < 450) ? x1g[b * 450 + tid] : 0.f;
    x0L[tid] = (tid < 450) ? x0g[b * 450 + tid] : 0.f;
  }
  if (tid < 160) uhat[tid] = 1.0f;      // u0 = 1 (f = 0)
  __syncthreads();

  // ---- distances into both tiles, track block max (over ca = full cover) ----
  float4 ca0, ca1, ca2, ca3, ca4, ca5, ca6, ca7, ca8, ca9;
  float4 rb0, rb1, rb2, rb3, rb4, rb5, rb6, rb7, rb8, rb9;
  float lmax = 0.f;
  {
    const float cx = x1L[jA * 3 + 0], cy = x1L[jA * 3 + 1], cz = x1L[jA * 3 + 2];
#define DCA(k) { \
    float tmp[4]; \
    _Pragma("unroll") \
    for (int c = 0; c < 4; ++c) { \
      const int row = rcb + 4 * k + c; \
      const float dx = x0L[row * 3 + 0] - cx; \
      const float dy = x0L[row * 3 + 1] - cy; \
      const float dz = x0L[row * 3 + 2] - cz; \
      float d = fmaf(dz, dz, fmaf(dy, dy, dx * dx)); \
      d = (act && row < N_) ? d : 0.f; \
      lmax = fmaxf(lmax, d); \
      tmp[c] = d; } \
    ca##k = make_float4(tmp[0], tmp[1], tmp[2], tmp[3]); }
    REP10(DCA)
#undef DCA
    const float rx = x0L[jA * 3 + 0], ry = x0L[jA * 3 + 1], rz = x0L[jA * 3 + 2];
#define DRB(k) { \
    float tmp[4]; \
    _Pragma("unroll") \
    for (int c = 0; c < 4; ++c) { \
      const int cc = rcb + 4 * k + c; \
      const float dx = rx - x1L[cc * 3 + 0]; \
      const float dy = ry - x1L[cc * 3 + 1]; \
      const float dz = rz - x1L[cc * 3 + 2]; \
      const float d = fmaf(dz, dz, fmaf(dy, dy, dx * dx)); \
      tmp[c] = (act && cc < N_) ? d : 0.f; } \
    rb##k = make_float4(tmp[0], tmp[1], tmp[2], tmp[3]); }
    REP10(DRB)
#undef DRB
  }
  #pragma unroll
  for (int off = 1; off < 64; off <<= 1) lmax = fmaxf(lmax, __shfl_xor(lmax, off));
  if (lane == 0) red[wid] = lmax;
  __syncthreads();
  if (tid == 0) {
    float m = red[0];
    #pragma unroll
    for (int w = 1; w < 10; ++w) m = fmaxf(m, red[w]);
    red[15] = -C1f / m;
  }
  __syncthreads();
  const float nsc = red[15];

  // ---- K = exp2(nsc * D); masked entries stay 0 ----
#define TOK(k) { \
    const int rA0 = rcb + 4 * k; \
    ca##k.x = (act && rA0 + 0 < N_) ? EXP2R(nsc * ca##k.x) : 0.f; \
    ca##k.y = (act && rA0 + 1 < N_) ? EXP2R(nsc * ca##k.y) : 0.f; \
    ca##k.z = (act && rA0 + 2 < N_) ? EXP2R(nsc * ca##k.z) : 0.f; \
    ca##k.w = (act && rA0 + 3 < N_) ? EXP2R(nsc * ca##k.w) : 0.f; \
    rb##k.x = (act && rA0 + 0 < N_) ? EXP2R(nsc * rb##k.x) : 0.f; \
    rb##k.y = (act && rA0 + 1 < N_) ? EXP2R(nsc * rb##k.y) : 0.f; \
    rb##k.z = (act && rA0 + 2 < N_) ? EXP2R(nsc * rb##k.z) : 0.f; \
    rb##k.w = (act && rA0 + 3 < N_) ? EXP2R(nsc * rb##k.w) : 0.f; }
  REP10(TOK)
#undef TOK

  const int ubase = 10 * qA;   // float4 index: uhat4/vhat4[ubase + k]

  // ---- 100 iterations: 2 barriers, no partial round-trips ----
  for (int it = 0; it < 100; ++it) {
    // phase A: s_j = sum_i K_ij u_i  (my col, 40 rows; b128 multicast u)
    {
      float s0 = 0.f, s1 = 0.f, s2 = 0.f, s3 = 0.f;
#define COLA(k) { \
      const float4 u4 = uhat4[ubase + k]; \
      s0 = fmaf(ca##k.x, u4.x, s0); \
      s1 = fmaf(ca##k.y, u4.y, s1); \
      s2 = fmaf(ca##k.z, u4.z, s2); \
      s3 = fmaf(ca##k.w, u4.w, s3); }
      REP10(COLA)
#undef COLA
      float s = (s0 + s1) + (s2 + s3);
      RED4_ADD(s)
      const float vh = __builtin_amdgcn_rcpf(fmaxf(s, 1e-37f)) * INV_N;
      if (qA == 0) vhat[jA] = vh;
    }
    __syncthreads();
    // phase B: t_i = sum_j K_ij v_j  (my row, 40 cols; b128 multicast v)
    {
      float t0 = 0.f, t1 = 0.f, t2 = 0.f, t3 = 0.f;
#define ROWB(k) { \
      const float4 v4 = vhat4[ubase + k]; \
      t0 = fmaf(rb##k.x, v4.x, t0); \
      t1 = fmaf(rb##k.y, v4.y, t1); \
      t2 = fmaf(rb##k.z, v4.z, t2); \
      t3 = fmaf(rb##k.w, v4.w, t3); }
      REP10(ROWB)
#undef ROWB
      float t = (t0 + t1) + (t2 + t3);
      RED4_ADD(t)
      const float uh = __builtin_amdgcn_rcpf(fmaxf(t, 1e-37f)) * INV_N;
      if (qA == 0) uhat[jA] = uh;
    }
    __syncthreads();
  }

  // ================== sampler (fused; psi/x tiles already local) ============
  if (tid < N_) {
    psiS[tid] = LOG2R(vhat[tid]);       // psi in log2 units
    mskS[tid] = maskg[b * 150 + tid];
    const uint32_t p = (uint32_t)(b * N_ + tid);
    const uint32_t hb = jax_bits(k1r0, k1r1, p);
    const uint32_t lb = jax_bits(k2r0, k2r1, p);
    iselS[tid] = (int)(((hb % 150u) * 46u + (lb % 150u)) % 150u);
  }
  const float tb = tg[b];
  __syncthreads();

  // S1: gumbel argmax per sample (wave per n), store y/u/mot
  for (int n = wid; n < N_; n += 10) {
    const uint32_t p = (uint32_t)(b * N_ + n);
    const int isel = iselS[n];
    const float xi0 = x0L[isel * 3 + 0], xi1 = x0L[isel * 3 + 1], xi2 = x0L[isel * 3 + 2];

    float best = -1e30f; int bestk = 0x7fffffff;
    #pragma unroll
    for (int c2 = 0; c2 < 3; ++c2) {
      const int k = lane + 64 * c2;
      if (k < N_) {
        const uint32_t bits = jax_bits(kj0, kj1, p * 150u + (uint32_t)k);
        float u = __uint_as_float((bits >> 9) | 0x3F800000u) - 1.0f;
        u = fmaxf(u, 1.17549435e-38f);
        const float nlu = -LN2f * LOG2R(u);
        const float g = -LN2f * LOG2R(nlu);
        const float dx = xi0 - x1L[k * 3 + 0];
        const float dy = xi1 - x1L[k * 3 + 1];
        const float dz = xi2 - x1L[k * 3 + 2];
        const float d2 = fmaf(dz, dz, fmaf(dy, dy, dx * dx));
        const float val = fmaf(psiS[k] + nsc * d2, LN2f, g);  // phi_i const over k
        if (val > best || (val == best && k < bestk)) { best = val; bestk = k; }
      }
    }
    #pragma unroll
    for (int off = 1; off < 64; off <<= 1) {
      const float ov = __shfl_xor(best, off);
      const int   ok = __shfl_xor(bestk, off);
      if (ov > best || (ov == best && ok < bestk)) { best = ov; bestk = ok; }
    }
    if (lane == 0) {
      const int j = bestk;
      const float mot = mskS[j];
      const float q0 = x1L[j * 3 + 0], q1 = x1L[j * 3 + 1], q2 = x1L[j * 3 + 2];
      const float omt = 1.f - tb;
      yu[n * 9 + 0] = xi0 * tb + q0 * omt + SIGMAf * epsg[b * 450 + n * 3 + 0];
      yu[n * 9 + 1] = xi1 * tb + q1 * omt + SIGMAf * epsg[b * 450 + n * 3 + 1];
      yu[n * 9 + 2] = xi2 * tb + q2 * omt + SIGMAf * epsg[b * 450 + n * 3 + 2];
      yu[n * 9 + 3] = (xi0 - q0) * mot;
      yu[n * 9 + 4] = (xi1 - q1) * mot;
      yu[n * 9 + 5] = (xi2 - q2) * mot;
      yu[n * 9 + 6] = mot;
    }
  }
  __syncthreads();

  // S2: MLP, lane = sample, hd loop uniform -> scalar W loads
  float loss = 0.f;
  if (wid < 3) {
    const int n = wid * 64 + lane;
    if (n < N_) {
      const float y0 = yu[n * 9 + 0], y1 = yu[n * 9 + 1], y2 = yu[n * 9 + 2];
      const float u0 = yu[n * 9 + 3], u1 = yu[n * 9 + 4], u2 = yu[n * 9 + 5];
      const float mot = yu[n * 9 + 6];
      float a0 = 0.f, a1 = 0.f, a2 = 0.f;
      #pragma unroll 4
      for (int hd = 0; hd < 512; ++hd) {
        float z = b1[hd];
        z = fmaf(y0, W1[hd],        z);
        z = fmaf(y1, W1[512 + hd],  z);
        z = fmaf(y2, W1[1024 + hd], z);
        z = fmaf(tb, W1[1536 + hd], z);
        const float zc = fmaf(0.044715f * z, z * z, z);
        const float e2 = EXP2R(-2.3022082062161855f * zc);
        const float ge = z * __builtin_amdgcn_rcpf(1.f + e2);
        a0 = fmaf(ge, W2[hd * 3 + 0], a0);
        a1 = fmaf(ge, W2[hd * 3 + 1], a1);
        a2 = fmaf(ge, W2[hd * 3 + 2], a2);
      }
      const float v0 = (a0 + b2[0]) * mot;
      const float v1 = (a1 + b2[1]) * mot;
      const float v2 = (a2 + b2[2]) * mot;
      const float d0 = v0 - u0, d1 = v1 - u1, d2 = v2 - u2;
      loss = fmaf(d2, d2, fmaf(d1, d1, d0 * d0));
    }
    #pragma unroll
    for (int off = 1; off < 64; off <<= 1) loss += __shfl_xor(loss, off);
    if (lane == 0) red[wid] = loss;
  }
  __syncthreads();
  if (tid == 0) partials[b] = red[0] + red[1] + red[2];
}

__global__ void cfm_reduce_kernel(const float* __restrict__ partials,
                                  float* __restrict__ out) {
  const int tid = threadIdx.x;   // 64 threads
  float s = 0.f;
  #pragma unroll
  for (int q = 0; q < 8; ++q) s += partials[tid + 64 * q];
  #pragma unroll
  for (int off = 1; off < 64; off <<= 1) s += __shfl_xor(s, off);
  if (tid == 0) out[0] = s * (1.0f / 230400.0f);
}

extern "C" void kernel_launch(void* const* d_in, const int* in_sizes, int n_in,
                              void* d_out, int out_size, void* d_ws, size_t ws_size,
                              hipStream_t stream) {
  (void)in_sizes; (void)n_in; (void)out_size; (void)ws_size;
  const float* x    = (const float*)d_in[0];
  const float* mask = (const float*)d_in[1];
  const float* t    = (const float*)d_in[2];
  const float* x0n  = (const float*)d_in[3];
  const float* epsn = (const float*)d_in[4];
  const float* W1   = (const float*)d_in[5];
  const float* b1   = (const float*)d_in[6];
  const float* W2   = (const float*)d_in[7];
  const float* b2   = (const float*)d_in[8];
  float* out = (float*)d_out;
  float* partials = (float*)d_ws;              // 512 floats

  uint32_t ki0, ki1, kj0, kj1, k1r0, k1r1, k2r0, k2r1;
  tf2x32(0u, 42u, 0u, 0u, ki0, ki1);
  tf2x32(0u, 42u, 0u, 1u, kj0, kj1);
  tf2x32(ki0, ki1, 0u, 0u, k1r0, k1r1);
  tf2x32(ki0, ki1, 0u, 1u, k2r0, k2r1);

  cfm_ot_kernel<<<B_, NT, 0, stream>>>(x, mask, t, x0n, epsn, W1, b1, W2, b2,
                                       partials,
                                       kj0, kj1, k1r0, k1r1, k2r0, k2r1);
  cfm_reduce_kernel<<<1, 64, 0, stream>>>(partials, out);
}

// Round 12
// 281.754 us; speedup vs baseline: 1.3917x; 1.3917x over previous
//
#include <hip/hip_runtime.h>
#include <cstdint>

#define B_ 512
#define N_ 150
#define NT 640
#define C1f 144.26950408889634f    // log2(e)/eps, eps=0.01
#define LN2f 0.69314718055994531f
#define SIGMAf 1.0e-4f
#define INV_N (1.0f/150.0f)

// raw hardware transcendentals (1-ULP v_exp_f32 / v_log_f32)
#define EXP2R(x) __builtin_amdgcn_exp2f(x)
#define LOG2R(x) __builtin_amdgcn_logf(x)

// DPP quad-perm reduces (VALU pipe): xor1 = 0xB1, xor2 = 0x4E
#define DPPF(v, c) __int_as_float(__builtin_amdgcn_update_dpp( \
    __float_as_int(v), __float_as_int(v), (c), 0xF, 0xF, false))
#define RED4_ADD(v)  { v = v + DPPF(v, 0xB1); v = v + DPPF(v, 0x4E); }

#define REP10(X) X(0) X(1) X(2) X(3) X(4) X(5) X(6) X(7) X(8) X(9)

// Threefry-2x32, 20 rounds, exactly as JAX's threefry2x32 lowering.
__host__ __device__ __forceinline__ void tf2x32(uint32_t k0, uint32_t k1,
                                                uint32_t x0, uint32_t x1,
                                                uint32_t& o0, uint32_t& o1) {
  uint32_t ks2 = k0 ^ k1 ^ 0x1BD11BDAu;
  x0 += k0; x1 += k1;
#define TFR(r) { x0 += x1; x1 = (x1 << r) | (x1 >> (32 - r)); x1 ^= x0; }
  TFR(13) TFR(15) TFR(26) TFR(6)
  x0 += k1;  x1 += ks2 + 1u;
  TFR(17) TFR(29) TFR(16) TFR(24)
  x0 += ks2; x1 += k0 + 2u;
  TFR(13) TFR(15) TFR(26) TFR(6)
  x0 += k0;  x1 += k1 + 3u;
  TFR(17) TFR(29) TFR(16) TFR(24)
  x0 += k1;  x1 += ks2 + 4u;
  TFR(13) TFR(15) TFR(26) TFR(6)
  x0 += ks2; x1 += k0 + 5u;
#undef TFR
  o0 = x0; o1 = x1;
}

__device__ __forceinline__ uint32_t jax_bits(uint32_t k0, uint32_t k1, uint32_t p) {
  uint32_t a, b; tf2x32(k0, k1, 0u, p, a, b);   // partitionable: counter (0, p)
  return a ^ b;
}

// ==== Fused kernel: Sinkhorn (static K, dual tile, 2 barriers) + sampling ===
// thread (jA = tid>>2, qA = tid&3):
//   ca tile: column jA, rows 40qA..+39   (phase A: colsum of K^T u)
//   rb tile: row    jA, cols 40qA..+39   (phase B: rowsum of K v)
// u/v consumed as aligned b128 multicast reads; single RED4 per phase.
// launch_bounds(NT,3): ~170-reg cap -> 80-float dual tile fits WITHOUT spill
// (R10's (NT,5) capped at ~102 regs and spilled to scratch: 167MB WRITE_SIZE).
__global__ __launch_bounds__(NT, 3) void cfm_ot_kernel(
    const float* __restrict__ x1g, const float* __restrict__ maskg,
    const float* __restrict__ tg, const float* __restrict__ x0g,
    const float* __restrict__ epsg,
    const float* __restrict__ W1, const float* __restrict__ b1,
    const float* __restrict__ W2, const float* __restrict__ b2,
    float* __restrict__ partials,
    uint32_t kj0, uint32_t kj1, uint32_t k1r0, uint32_t k1r1,
    uint32_t k2r0, uint32_t k2r1)
{
  __shared__ float x1L[480], x0L[480];
  __shared__ __align__(16) float vhat[160];
  __shared__ __align__(16) float uhat[160];
  __shared__ float red[16];
  __shared__ float psiS[152], mskS[152];
  __shared__ float yu[150 * 9];
  __shared__ int   iselS[152];
  float4* vhat4 = (float4*)vhat;
  float4* uhat4 = (float4*)uhat;

  const int b    = blockIdx.x;
  const int tid  = threadIdx.x;
  const int lane = tid & 63;
  const int wid  = tid >> 6;
  const int jA   = tid >> 2;      // 0..159: column (A) / row (B)
  const int qA   = tid & 3;       // 40-element chunk
  const int rcb  = 40 * qA;
  const bool act = (jA < N_);

  if (tid < 480) {
    x1L[tid] = (tid < 450) ? x1g[b * 450 + tid] : 0.f;
    x0L[tid] = (tid < 450) ? x0g[b * 450 + tid] : 0.f;
  }
  if (tid < 160) uhat[tid] = 1.0f;      // u0 = 1 (f = 0)
  __syncthreads();

  // ---- distances into both tiles, track block max (over ca = full cover) ----
  float4 ca0, ca1, ca2, ca3, ca4, ca5, ca6, ca7, ca8, ca9;
  float4 rb0, rb1, rb2, rb3, rb4, rb5, rb6, rb7, rb8, rb9;
  float lmax = 0.f;
  {
    const float cx = x1L[jA * 3 + 0], cy = x1L[jA * 3 + 1], cz = x1L[jA * 3 + 2];
#define DCA(k) { \
    float tmp[4]; \
    _Pragma("unroll") \
    for (int c = 0; c < 4; ++c) { \
      const int row = rcb + 4 * k + c; \
      const float dx = x0L[row * 3 + 0] - cx; \
      const float dy = x0L[row * 3 + 1] - cy; \
      const float dz = x0L[row * 3 + 2] - cz; \
      float d = fmaf(dz, dz, fmaf(dy, dy, dx * dx)); \
      d = (act && row < N_) ? d : 0.f; \
      lmax = fmaxf(lmax, d); \
      tmp[c] = d; } \
    ca##k = make_float4(tmp[0], tmp[1], tmp[2], tmp[3]); }
    REP10(DCA)
#undef DCA
    const float rx = x0L[jA * 3 + 0], ry = x0L[jA * 3 + 1], rz = x0L[jA * 3 + 2];
#define DRB(k) { \
    float tmp[4]; \
    _Pragma("unroll") \
    for (int c = 0; c < 4; ++c) { \
      const int cc = rcb + 4 * k + c; \
      const float dx = rx - x1L[cc * 3 + 0]; \
      const float dy = ry - x1L[cc * 3 + 1]; \
      const float dz = rz - x1L[cc * 3 + 2]; \
      const float d = fmaf(dz, dz, fmaf(dy, dy, dx * dx)); \
      tmp[c] = (act && cc < N_) ? d : 0.f; } \
    rb##k = make_float4(tmp[0], tmp[1], tmp[2], tmp[3]); }
    REP10(DRB)
#undef DRB
  }
  #pragma unroll
  for (int off = 1; off < 64; off <<= 1) lmax = fmaxf(lmax, __shfl_xor(lmax, off));
  if (lane == 0) red[wid] = lmax;
  __syncthreads();
  if (tid == 0) {
    float m = red[0];
    #pragma unroll
    for (int w = 1; w < 10; ++w) m = fmaxf(m, red[w]);
    red[15] = -C1f / m;
  }
  __syncthreads();
  const float nsc = red[15];

  // ---- K = exp2(nsc * D); masked entries stay 0 ----
#define TOK(k) { \
    const int rA0 = rcb + 4 * k; \
    ca##k.x = (act && rA0 + 0 < N_) ? EXP2R(nsc * ca##k.x) : 0.f; \
    ca##k.y = (act && rA0 + 1 < N_) ? EXP2R(nsc * ca##k.y) : 0.f; \
    ca##k.z = (act && rA0 + 2 < N_) ? EXP2R(nsc * ca##k.z) : 0.f; \
    ca##k.w = (act && rA0 + 3 < N_) ? EXP2R(nsc * ca##k.w) : 0.f; \
    rb##k.x = (act && rA0 + 0 < N_) ? EXP2R(nsc * rb##k.x) : 0.f; \
    rb##k.y = (act && rA0 + 1 < N_) ? EXP2R(nsc * rb##k.y) : 0.f; \
    rb##k.z = (act && rA0 + 2 < N_) ? EXP2R(nsc * rb##k.z) : 0.f; \
    rb##k.w = (act && rA0 + 3 < N_) ? EXP2R(nsc * rb##k.w) : 0.f; }
  REP10(TOK)
#undef TOK

  const int ubase = 10 * qA;   // float4 index: uhat4/vhat4[ubase + k]

  // ---- 100 iterations: 2 barriers, no partial round-trips ----
  for (int it = 0; it < 100; ++it) {
    // phase A: s_j = sum_i K_ij u_i  (my col, 40 rows; b128 multicast u)
    {
      float s0 = 0.f, s1 = 0.f, s2 = 0.f, s3 = 0.f;
#define COLA(k) { \
      const float4 u4 = uhat4[ubase + k]; \
      s0 = fmaf(ca##k.x, u4.x, s0); \
      s1 = fmaf(ca##k.y, u4.y, s1); \
      s2 = fmaf(ca##k.z, u4.z, s2); \
      s3 = fmaf(ca##k.w, u4.w, s3); }
      REP10(COLA)
#undef COLA
      float s = (s0 + s1) + (s2 + s3);
      RED4_ADD(s)
      const float vh = __builtin_amdgcn_rcpf(fmaxf(s, 1e-37f)) * INV_N;
      if (qA == 0) vhat[jA] = vh;
    }
    __syncthreads();
    // phase B: t_i = sum_j K_ij v_j  (my row, 40 cols; b128 multicast v)
    {
      float t0 = 0.f, t1 = 0.f, t2 = 0.f, t3 = 0.f;
#define ROWB(k) { \
      const float4 v4 = vhat4[ubase + k]; \
      t0 = fmaf(rb##k.x, v4.x, t0); \
      t1 = fmaf(rb##k.y, v4.y, t1); \
      t2 = fmaf(rb##k.z, v4.z, t2); \
      t3 = fmaf(rb##k.w, v4.w, t3); }
      REP10(ROWB)
#undef ROWB
      float t = (t0 + t1) + (t2 + t3);
      RED4_ADD(t)
      const float uh = __builtin_amdgcn_rcpf(fmaxf(t, 1e-37f)) * INV_N;
      if (qA == 0) uhat[jA] = uh;
    }
    __syncthreads();
  }

  // ================== sampler (fused; psi/x tiles already local) ============
  if (tid < N_) {
    psiS[tid] = LOG2R(vhat[tid]);       // psi in log2 units
    mskS[tid] = maskg[b * 150 + tid];
    const uint32_t p = (uint32_t)(b * N_ + tid);
    const uint32_t hb = jax_bits(k1r0, k1r1, p);
    const uint32_t lb = jax_bits(k2r0, k2r1, p);
    iselS[tid] = (int)(((hb % 150u) * 46u + (lb % 150u)) % 150u);
  }
  const float tb = tg[b];
  __syncthreads();

  // S1: gumbel argmax per sample (wave per n), store y/u/mot
  for (int n = wid; n < N_; n += 10) {
    const uint32_t p = (uint32_t)(b * N_ + n);
    const int isel = iselS[n];
    const float xi0 = x0L[isel * 3 + 0], xi1 = x0L[isel * 3 + 1], xi2 = x0L[isel * 3 + 2];

    float best = -1e30f; int bestk = 0x7fffffff;
    #pragma unroll
    for (int c2 = 0; c2 < 3; ++c2) {
      const int k = lane + 64 * c2;
      if (k < N_) {
        const uint32_t bits = jax_bits(kj0, kj1, p * 150u + (uint32_t)k);
        float u = __uint_as_float((bits >> 9) | 0x3F800000u) - 1.0f;
        u = fmaxf(u, 1.17549435e-38f);
        const float nlu = -LN2f * LOG2R(u);
        const float g = -LN2f * LOG2R(nlu);
        const float dx = xi0 - x1L[k * 3 + 0];
        const float dy = xi1 - x1L[k * 3 + 1];
        const float dz = xi2 - x1L[k * 3 + 2];
        const float d2 = fmaf(dz, dz, fmaf(dy, dy, dx * dx));
        const float val = fmaf(psiS[k] + nsc * d2, LN2f, g);  // phi_i const over k
        if (val > best || (val == best && k < bestk)) { best = val; bestk = k; }
      }
    }
    #pragma unroll
    for (int off = 1; off < 64; off <<= 1) {
      const float ov = __shfl_xor(best, off);
      const int   ok = __shfl_xor(bestk, off);
      if (ov > best || (ov == best && ok < bestk)) { best = ov; bestk = ok; }
    }
    if (lane == 0) {
      const int j = bestk;
      const float mot = mskS[j];
      const float q0 = x1L[j * 3 + 0], q1 = x1L[j * 3 + 1], q2 = x1L[j * 3 + 2];
      const float omt = 1.f - tb;
      yu[n * 9 + 0] = xi0 * tb + q0 * omt + SIGMAf * epsg[b * 450 + n * 3 + 0];
      yu[n * 9 + 1] = xi1 * tb + q1 * omt + SIGMAf * epsg[b * 450 + n * 3 + 1];
      yu[n * 9 + 2] = xi2 * tb + q2 * omt + SIGMAf * epsg[b * 450 + n * 3 + 2];
      yu[n * 9 + 3] = (xi0 - q0) * mot;
      yu[n * 9 + 4] = (xi1 - q1) * mot;
      yu[n * 9 + 5] = (xi2 - q2) * mot;
      yu[n * 9 + 6] = mot;
    }
  }
  __syncthreads();

  // S2: MLP, lane = sample, hd loop uniform -> scalar W loads
  float loss = 0.f;
  if (wid < 3) {
    const int n = wid * 64 + lane;
    if (n < N_) {
      const float y0 = yu[n * 9 + 0], y1 = yu[n * 9 + 1], y2 = yu[n * 9 + 2];
      const float u0 = yu[n * 9 + 3], u1 = yu[n * 9 + 4], u2 = yu[n * 9 + 5];
      const float mot = yu[n * 9 + 6];
      float a0 = 0.f, a1 = 0.f, a2 = 0.f;
      #pragma unroll 4
      for (int hd = 0; hd < 512; ++hd) {
        float z = b1[hd];
        z = fmaf(y0, W1[hd],        z);
        z = fmaf(y1, W1[512 + hd],  z);
        z = fmaf(y2, W1[1024 + hd], z);
        z = fmaf(tb, W1[1536 + hd], z);
        const float zc = fmaf(0.044715f * z, z * z, z);
        const float e2 = EXP2R(-2.3022082062161855f * zc);
        const float ge = z * __builtin_amdgcn_rcpf(1.f + e2);
        a0 = fmaf(ge, W2[hd * 3 + 0], a0);
        a1 = fmaf(ge, W2[hd * 3 + 1], a1);
        a2 = fmaf(ge, W2[hd * 3 + 2], a2);
      }
      const float v0 = (a0 + b2[0]) * mot;
      const float v1 = (a1 + b2[1]) * mot;
      const float v2 = (a2 + b2[2]) * mot;
      const float d0 = v0 - u0, d1 = v1 - u1, d2 = v2 - u2;
      loss = fmaf(d2, d2, fmaf(d1, d1, d0 * d0));
    }
    #pragma unroll
    for (int off = 1; off < 64; off <<= 1) loss += __shfl_xor(loss, off);
    if (lane == 0) red[wid] = loss;
  }
  __syncthreads();
  if (tid == 0) partials[b] = red[0] + red[1] + red[2];
}

__global__ void cfm_reduce_kernel(const float* __restrict__ partials,
                                  float* __restrict__ out) {
  const int tid = threadIdx.x;   // 64 threads
  float s = 0.f;
  #pragma unroll
  for (int q = 0; q < 8; ++q) s += partials[tid + 64 * q];
  #pragma unroll
  for (int off = 1; off < 64; off <<= 1) s += __shfl_xor(s, off);
  if (tid == 0) out[0] = s * (1.0f / 230400.0f);
}

extern "C" void kernel_launch(void* const* d_in, const int* in_sizes, int n_in,
                              void* d_out, int out_size, void* d_ws, size_t ws_size,
                              hipStream_t stream) {
  (void)in_sizes; (void)n_in; (void)out_size; (void)ws_size;
  const float* x    = (const float*)d_in[0];
  const float* mask = (const float*)d_in[1];
  const float* t    = (const float*)d_in[2];
  const float* x0n  = (const float*)d_in[3];
  const float* epsn = (const float*)d_in[4];
  const float* W1   = (const float*)d_in[5];
  const float* b1   = (const float*)d_in[6];
  const float* W2   = (const float*)d_in[7];
  const float* b2   = (const float*)d_in[8];
  float* out = (float*)d_out;
  float* partials = (float*)d_ws;              // 512 floats

  uint32_t ki0, ki1, kj0, kj1, k1r0, k1r1, k2r0, k2r1;
  tf2x32(0u, 42u, 0u, 0u, ki0, ki1);
  tf2x32(0u, 42u, 0u, 1u, kj0, kj1);
  tf2x32(ki0, ki1, 0u, 0u, k1r0, k1r1);
  tf2x32(ki0, ki1, 0u, 1u, k2r0, k2r1);

  cfm_ot_kernel<<<B_, NT, 0, stream>>>(x, mask, t, x0n, epsn, W1, b1, W2, b2,
                                       partials,
                                       kj0, kj1, k1r0, k1r1, k2r0, k2r1);
  cfm_reduce_kernel<<<1, 64, 0, stream>>>(partials, out);
}